// Round 5
// baseline (435.644 us; speedup 1.0000x reference)
//
#include <hip/hip_runtime.h>

#define Bb 4
#define Nn 1024
#define Dd 512
#define Hh 8
#define Ee 5
#define HDd 64

typedef unsigned int u32_t;
typedef unsigned short u16_t;
typedef unsigned char u8_t;
typedef short s16x8 __attribute__((ext_vector_type(8)));
typedef float f32x4 __attribute__((ext_vector_type(4)));

#define MFMA(a, b, c) __builtin_amdgcn_mfma_f32_16x16x32_bf16((a), (b), (c), 0, 0, 0)

// fp32 -> (hi16 truncated bf16) | (lo16 RN-bf16 of remainder); hi+lo ~= x (rel err ~2^-17)
__device__ __forceinline__ u32_t pack32(float x) {
    u32_t u = __float_as_uint(x);
    u32_t hi = u & 0xffff0000u;
    float rem = x - __uint_as_float(hi);
    u32_t r = __float_as_uint(rem);
    u32_t lo = (r + 0x7fffu + ((r >> 16) & 1u)) >> 16;
    return hi | (lo & 0xffffu);
}

// fp32 -> RN bf16
__device__ __forceinline__ u16_t rn16(float x) {
    u32_t u = __float_as_uint(x);
    return (u16_t)((u + 0x7fffu + ((u >> 16) & 1u)) >> 16);
}

__device__ __forceinline__ float bf2f(u16_t v) { return __uint_as_float(((u32_t)v) << 16); }

// 8 packed u32 (two uint4) -> hi bf16x8, lo bf16x8
__device__ __forceinline__ void unpk8(uint4 A, uint4 B, s16x8& h, s16x8& l) {
    union { u16_t u[8]; s16x8 v; } H, L;
    u32_t a[8] = {A.x, A.y, A.z, A.w, B.x, B.y, B.z, B.w};
    #pragma unroll
    for (int i = 0; i < 8; i++) { H.u[i] = (u16_t)(a[i] >> 16); L.u[i] = (u16_t)(a[i] & 0xffffu); }
    h = H.v; l = L.v;
}

// ---------- K0: normalize node_mask -> mw[4096], anyB[4] ----------
__global__ __launch_bounds__(256) void prep_mask(const void* __restrict__ msk,
                                                 int* __restrict__ mw,
                                                 int* __restrict__ anyB) {
    __shared__ int notint;
    __shared__ int ab[Bb];
    const int tid = threadIdx.x;
    if (tid == 0) notint = 0;
    if (tid < Bb) ab[tid] = 0;
    __syncthreads();
    const u32_t* wp = (const u32_t*)msk;
    int bad = 0;
    for (int i = tid; i < 1024; i += 256) bad |= (wp[i] > 1u);
    if (bad) atomicOr(&notint, 1);
    __syncthreads();
    const int isbyte = notint;
    const u8_t* bp = (const u8_t*)msk;
    for (int i = tid; i < Bb * Nn; i += 256) {
        const int v = isbyte ? (bp[i] != 0) : (wp[i] != 0);
        mw[i] = v;
        if (v) atomicOr(&ab[i >> 10], 1);
    }
    __syncthreads();
    if (tid < Bb) anyB[tid] = ab[tid];
}

// ---------- K1: split x, w_qkv, w_proj into bf16 hi/lo ----------
__global__ __launch_bounds__(256) void presplit(const float* __restrict__ x,
                                                const float* __restrict__ wq,
                                                const float* __restrict__ wp,
                                                u16_t* __restrict__ xh, u16_t* __restrict__ xl,
                                                u16_t* __restrict__ wqh, u16_t* __restrict__ wql,
                                                u16_t* __restrict__ wph, u16_t* __restrict__ wpl) {
    const int i = blockIdx.x * 256 + threadIdx.x;  // < 3145728
    const float* src; u16_t *dh, *dl; int off;
    if (i < 2097152)      { src = x;  dh = xh;  dl = xl;  off = i; }
    else if (i < 2883584) { src = wq; dh = wqh; dl = wql; off = i - 2097152; }
    else                  { src = wp; dh = wph; dl = wpl; off = i - 2883584; }
    const u32_t p = pack32(src[off]);
    dh[off] = (u16_t)(p >> 16);
    dl[off] = (u16_t)(p & 0xffffu);
}

// ---------- K2: gb[h][b][i][j] = sigmoid(ef.weg + beg) * (ef.wep), RN bf16 ----------
__global__ __launch_bounds__(256) void gb_pre(const float* __restrict__ ef,
                                              const float* __restrict__ wep,
                                              const float* __restrict__ weg,
                                              const float* __restrict__ beg,
                                              u16_t* __restrict__ gb) {
    const size_t t = (size_t)blockIdx.x * 256 + threadIdx.x;  // < B*N*N
    const float* ep = ef + t * Ee;
    const float e0 = ep[0], e1 = ep[1], e2 = ep[2], e3 = ep[3], e4 = ep[4];
    #pragma unroll
    for (int h = 0; h < Hh; h++) {
        const float bias = fmaf(e0, wep[h*Ee+0], fmaf(e1, wep[h*Ee+1], fmaf(e2, wep[h*Ee+2],
                           fmaf(e3, wep[h*Ee+3], e4 * wep[h*Ee+4]))));
        const float gv = fmaf(e0, weg[h*Ee+0], fmaf(e1, weg[h*Ee+1], fmaf(e2, weg[h*Ee+2],
                         fmaf(e3, weg[h*Ee+3], fmaf(e4, weg[h*Ee+4], beg[h])))));
        const float gate = 1.f / (1.f + __expf(-gv));
        gb[(size_t)h * (Bb * Nn * (size_t)Nn) + t] = rn16(gate * bias);
    }
}

// ---------- K3: qkv GEMM, direct-global frags, no LDS. Block 64x64, wave 32x32 ----------
__global__ __launch_bounds__(256) void qkv_mfma(const u16_t* __restrict__ xh, const u16_t* __restrict__ xl,
                                                const u16_t* __restrict__ wh, const u16_t* __restrict__ wl,
                                                u16_t* __restrict__ qh, u16_t* __restrict__ ql,
                                                u16_t* __restrict__ kh, u16_t* __restrict__ kl,
                                                u16_t* __restrict__ vh, u16_t* __restrict__ vl) {
    const int tid = threadIdx.x, lane = tid & 63, wv = tid >> 6;
    const int lm = lane & 15, quad = lane >> 4;
    const int mh = wv >> 1, nh = wv & 1;
    const int m0 = blockIdx.y * 64, c0 = blockIdx.x * 64;

    f32x4 acc[2][2];
    #pragma unroll
    for (int mt = 0; mt < 2; mt++)
        #pragma unroll
        for (int nt = 0; nt < 2; nt++) acc[mt][nt] = {0.f, 0.f, 0.f, 0.f};

    for (int kt = 0; kt < 8; kt++) {
        const int kb = kt * 64;
        s16x8 ah[2][2], al[2][2], bh[2][2], bl[2][2];
        #pragma unroll
        for (int mt = 0; mt < 2; mt++) {
            const size_t row = (size_t)(m0 + 32 * mh + 16 * mt + lm) * Dd + kb + quad * 8;
            #pragma unroll
            for (int ks = 0; ks < 2; ks++) {
                ah[mt][ks] = *(const s16x8*)(xh + row + ks * 32);
                al[mt][ks] = *(const s16x8*)(xl + row + ks * 32);
            }
        }
        #pragma unroll
        for (int nt = 0; nt < 2; nt++) {
            const size_t row = (size_t)(c0 + 32 * nh + 16 * nt + lm) * Dd + kb + quad * 8;
            #pragma unroll
            for (int ks = 0; ks < 2; ks++) {
                bh[nt][ks] = *(const s16x8*)(wh + row + ks * 32);
                bl[nt][ks] = *(const s16x8*)(wl + row + ks * 32);
            }
        }
        #pragma unroll
        for (int mt = 0; mt < 2; mt++)
            #pragma unroll
            for (int nt = 0; nt < 2; nt++)
                #pragma unroll
                for (int ks = 0; ks < 2; ks++) {
                    acc[mt][nt] = MFMA(ah[mt][ks], bh[nt][ks], acc[mt][nt]);
                    acc[mt][nt] = MFMA(ah[mt][ks], bl[nt][ks], acc[mt][nt]);
                    acc[mt][nt] = MFMA(al[mt][ks], bh[nt][ks], acc[mt][nt]);
                }
    }
    #pragma unroll
    for (int nt = 0; nt < 2; nt++) {
        const int c = c0 + 32 * nh + 16 * nt + lm;
        const int s = c >> 9, hd = c & 511, h = hd >> 6, d = hd & 63;
        u16_t* dh = (s == 0) ? qh : (s == 1) ? kh : vh;
        u16_t* dl = (s == 0) ? ql : (s == 1) ? kl : vl;
        #pragma unroll
        for (int mt = 0; mt < 2; mt++)
            #pragma unroll
            for (int r = 0; r < 4; r++) {
                const int m = m0 + 32 * mh + 16 * mt + 4 * quad + r;
                const int b = m >> 10, n = m & (Nn - 1);
                const size_t o = (((size_t)b * Hh + h) * Nn + n) * HDd + d;
                const u32_t p = pack32(acc[mt][nt][r]);
                dh[o] = (u16_t)(p >> 16);
                dl[o] = (u16_t)(p & 0xffffu);
            }
    }
}

// ---------- K4: flash attention. Q/K frags direct-global; V,P via LDS ----------
__global__ __launch_bounds__(256, 4) void attn_mfma(const u16_t* __restrict__ qh, const u16_t* __restrict__ ql,
                                                    const u16_t* __restrict__ kh, const u16_t* __restrict__ kl,
                                                    const u16_t* __restrict__ vh, const u16_t* __restrict__ vl,
                                                    const u16_t* __restrict__ gb,
                                                    const int* __restrict__ mw,
                                                    const int* __restrict__ anyB,
                                                    u16_t* __restrict__ aoh, u16_t* __restrict__ aol) {
    __shared__ __align__(16) u16_t VTh[64 * 72], VTl[64 * 72];   // VT[d][j], stride 72
    __shared__ __align__(16) u32_t Pk[64 * 68];                  // packed P, stride 68

    const int tid = threadIdx.x;
    const int wv = tid >> 6, lane = tid & 63, lm = lane & 15, quad = lane >> 4;
    const int i0 = blockIdx.x * 64;
    const int h  = blockIdx.y;
    const int b  = blockIdx.z;

    const size_t plane = (((size_t)b * Hh + h) * Nn) * HDd;
    const u16_t* khp = kh + plane;
    const u16_t* klp = kl + plane;
    const u16_t* vhp = vh + plane;
    const u16_t* vlp = vl + plane;
    const u16_t* gbq = gb + (((size_t)h * Bb + b) << 20);
    const int* mwB = mw + b * Nn;

    // Q frags once, direct from global: A[m=lm][k=ks*32+quad*8+j]
    s16x8 qfh[2], qfl[2];
    {
        const size_t row = plane + (size_t)(i0 + 16 * wv + lm) * HDd + quad * 8;
        #pragma unroll
        for (int ks = 0; ks < 2; ks++) {
            qfh[ks] = *(const s16x8*)(qh + row + ks * 32);
            qfl[ks] = *(const s16x8*)(ql + row + ks * 32);
        }
    }

    const int anyb = anyB[b];
    int rv[4];
    float m_[4], l_[4];
    f32x4 accO[4];
    #pragma unroll
    for (int r = 0; r < 4; r++) {
        rv[r] = anyb && mwB[i0 + 16 * wv + 4 * quad + r];
        m_[r] = -1e30f; l_[r] = 0.f;
    }
    #pragma unroll
    for (int dn = 0; dn < 4; dn++) accO[dn] = {0.f, 0.f, 0.f, 0.f};

    const int jg = tid >> 4, dc = tid & 15;   // VT staging roles

    for (int jt = 0; jt < Nn / 64; jt++) {
        const int j0 = jt * 64;
        __syncthreads();   // previous tile's VT fully consumed

        // ---- stage VT[d][j] (transpose V rows) ----
        {
            u32_t rh[4][2], rl[4][2];
            #pragma unroll
            for (int jj = 0; jj < 4; jj++) {
                const size_t o = (size_t)(j0 + 4 * jg + jj) * HDd + 4 * dc;
                uint2 A = *(const uint2*)(vhp + o);
                uint2 B = *(const uint2*)(vlp + o);
                rh[jj][0] = A.x; rh[jj][1] = A.y;
                rl[jj][0] = B.x; rl[jj][1] = B.y;
            }
            #pragma unroll
            for (int cc = 0; cc < 4; cc++) {
                const int d = 4 * dc + cc;
                const int w = cc >> 1, sh = (cc & 1) * 16;
                uint2 oh, ol;
                oh.x = ((rh[0][w] >> sh) & 0xffffu) | (((rh[1][w] >> sh) & 0xffffu) << 16);
                oh.y = ((rh[2][w] >> sh) & 0xffffu) | (((rh[3][w] >> sh) & 0xffffu) << 16);
                ol.x = ((rl[0][w] >> sh) & 0xffffu) | (((rl[1][w] >> sh) & 0xffffu) << 16);
                ol.y = ((rl[2][w] >> sh) & 0xffffu) | (((rl[3][w] >> sh) & 0xffffu) << 16);
                *(uint2*)&VTh[d * 72 + 4 * jg] = oh;
                *(uint2*)&VTl[d * 72 + 4 * jg] = ol;
            }
        }

        // ---- QK^T: K frags direct from global (no LDS dependency -> overlaps staging) ----
        f32x4 S[4];
        #pragma unroll
        for (int jn = 0; jn < 4; jn++) {
            const size_t row = (size_t)(j0 + 16 * jn + lm) * HDd + quad * 8;
            f32x4 s = {0.f, 0.f, 0.f, 0.f};
            #pragma unroll
            for (int ks = 0; ks < 2; ks++) {
                s16x8 bh = *(const s16x8*)(khp + row + ks * 32);
                s16x8 bl = *(const s16x8*)(klp + row + ks * 32);
                s = MFMA(qfh[ks], bh, s);
                s = MFMA(qfh[ks], bl, s);
                s = MFMA(qfl[ks], bh, s);
            }
            S[jn] = s;
        }

        int mj[4];
        #pragma unroll
        for (int jn = 0; jn < 4; jn++) mj[jn] = mwB[j0 + 16 * jn + lm];

        __syncthreads();   // VT ready

        // ---- scores (S*scale + gb) + mask + online softmax; write P (own rows) ----
        #pragma unroll
        for (int r = 0; r < 4; r++) {
            const int i = i0 + 16 * wv + 4 * quad + r;
            float sv[4];
            #pragma unroll
            for (int jn = 0; jn < 4; jn++) {
                if (!rv[r]) {
                    sv[jn] = 0.f;
                } else if (!mj[jn]) {
                    sv[jn] = -1e30f;
                } else {
                    const float g = bf2f(gbq[(size_t)i * Nn + j0 + 16 * jn + lm]);
                    sv[jn] = fmaf(S[jn][r], 0.125f, g);
                }
            }
            float tmax = fmaxf(fmaxf(sv[0], sv[1]), fmaxf(sv[2], sv[3]));
            tmax = fmaxf(tmax, __shfl_xor(tmax, 1));
            tmax = fmaxf(tmax, __shfl_xor(tmax, 2));
            tmax = fmaxf(tmax, __shfl_xor(tmax, 4));
            tmax = fmaxf(tmax, __shfl_xor(tmax, 8));
            const float mnew = fmaxf(m_[r], tmax);
            const float alpha = __expf(m_[r] - mnew);
            float p[4], ps = 0.f;
            #pragma unroll
            for (int jn = 0; jn < 4; jn++) { p[jn] = __expf(sv[jn] - mnew); ps += p[jn]; }
            ps += __shfl_xor(ps, 1);
            ps += __shfl_xor(ps, 2);
            ps += __shfl_xor(ps, 4);
            ps += __shfl_xor(ps, 8);
            m_[r] = mnew;
            l_[r] = l_[r] * alpha + ps;
            #pragma unroll
            for (int dn = 0; dn < 4; dn++) accO[dn][r] *= alpha;
            #pragma unroll
            for (int jn = 0; jn < 4; jn++)
                Pk[(16 * wv + 4 * quad + r) * 68 + 16 * jn + lm] = pack32(p[jn]);
        }

        // ---- PV: P frags from own rows (no barrier needed), V frags from LDS ----
        s16x8 ph[2], pl[2];
        #pragma unroll
        for (int ks2 = 0; ks2 < 2; ks2++) {
            const int off = (16 * wv + lm) * 68 + ks2 * 32 + quad * 8;
            uint4 A = *(const uint4*)&Pk[off];
            uint4 B = *(const uint4*)&Pk[off + 4];
            unpk8(A, B, ph[ks2], pl[ks2]);
        }
        #pragma unroll
        for (int dn = 0; dn < 4; dn++) {
            f32x4 c = accO[dn];
            #pragma unroll
            for (int ks2 = 0; ks2 < 2; ks2++) {
                s16x8 vvh = *(const s16x8*)&VTh[(16 * dn + lm) * 72 + ks2 * 32 + quad * 8];
                s16x8 vvl = *(const s16x8*)&VTl[(16 * dn + lm) * 72 + ks2 * 32 + quad * 8];
                c = MFMA(ph[ks2], vvh, c);
                c = MFMA(ph[ks2], vvl, c);
                c = MFMA(pl[ks2], vvh, c);
            }
            accO[dn] = c;
        }
    }

    #pragma unroll
    for (int r = 0; r < 4; r++) {
        const int i = i0 + 16 * wv + 4 * quad + r;
        const float inv = 1.f / l_[r];
        #pragma unroll
        for (int dn = 0; dn < 4; dn++) {
            const size_t o = (size_t)(b * Nn + i) * Dd + h * HDd + 16 * dn + lm;
            const u32_t p = pack32(accO[dn][r] * inv);
            aoh[o] = (u16_t)(p >> 16);
            aol[o] = (u16_t)(p & 0xffffu);
        }
    }
}

// ---------- K5: out = ao @ w_proj^T + bias, direct-global frags ----------
__global__ __launch_bounds__(256) void out_mfma(const u16_t* __restrict__ ah_, const u16_t* __restrict__ al_,
                                                const u16_t* __restrict__ wh, const u16_t* __restrict__ wl,
                                                const float* __restrict__ bias,
                                                float* __restrict__ out) {
    const int tid = threadIdx.x, lane = tid & 63, wv = tid >> 6;
    const int lm = lane & 15, quad = lane >> 4;
    const int mh = wv >> 1, nh = wv & 1;
    const int m0 = blockIdx.y * 64, c0 = blockIdx.x * 64;

    f32x4 acc[2][2];
    #pragma unroll
    for (int mt = 0; mt < 2; mt++)
        #pragma unroll
        for (int nt = 0; nt < 2; nt++) acc[mt][nt] = {0.f, 0.f, 0.f, 0.f};

    for (int kt = 0; kt < 8; kt++) {
        const int kb = kt * 64;
        s16x8 ah[2][2], al[2][2], bh[2][2], bl[2][2];
        #pragma unroll
        for (int mt = 0; mt < 2; mt++) {
            const size_t row = (size_t)(m0 + 32 * mh + 16 * mt + lm) * Dd + kb + quad * 8;
            #pragma unroll
            for (int ks = 0; ks < 2; ks++) {
                ah[mt][ks] = *(const s16x8*)(ah_ + row + ks * 32);
                al[mt][ks] = *(const s16x8*)(al_ + row + ks * 32);
            }
        }
        #pragma unroll
        for (int nt = 0; nt < 2; nt++) {
            const size_t row = (size_t)(c0 + 32 * nh + 16 * nt + lm) * Dd + kb + quad * 8;
            #pragma unroll
            for (int ks = 0; ks < 2; ks++) {
                bh[nt][ks] = *(const s16x8*)(wh + row + ks * 32);
                bl[nt][ks] = *(const s16x8*)(wl + row + ks * 32);
            }
        }
        #pragma unroll
        for (int mt = 0; mt < 2; mt++)
            #pragma unroll
            for (int nt = 0; nt < 2; nt++)
                #pragma unroll
                for (int ks = 0; ks < 2; ks++) {
                    acc[mt][nt] = MFMA(ah[mt][ks], bh[nt][ks], acc[mt][nt]);
                    acc[mt][nt] = MFMA(ah[mt][ks], bl[nt][ks], acc[mt][nt]);
                    acc[mt][nt] = MFMA(al[mt][ks], bh[nt][ks], acc[mt][nt]);
                }
    }
    #pragma unroll
    for (int nt = 0; nt < 2; nt++) {
        const int c = c0 + 32 * nh + 16 * nt + lm;
        const float bc = bias[c];
        #pragma unroll
        for (int mt = 0; mt < 2; mt++)
            #pragma unroll
            for (int r = 0; r < 4; r++) {
                const int m = m0 + 32 * mh + 16 * mt + 4 * quad + r;
                out[(size_t)m * Dd + c] = acc[mt][nt][r] + bc;
            }
    }
}

extern "C" void kernel_launch(void* const* d_in, const int* in_sizes, int n_in,
                              void* d_out, int out_size, void* d_ws, size_t ws_size,
                              hipStream_t stream) {
    const float* x    = (const float*)d_in[0];
    const float* ef   = (const float*)d_in[1];
    const void*  msk  = d_in[2];
    const float* wqkv = (const float*)d_in[3];
    const float* wep  = (const float*)d_in[4];
    const float* weg  = (const float*)d_in[5];
    const float* beg  = (const float*)d_in[6];
    const float* wpj  = (const float*)d_in[7];
    const float* bpj  = (const float*)d_in[8];
    float* out = (float*)d_out;

    u8_t* p = (u8_t*)d_ws;
    int* mw    = (int*)p;           p += 16384;
    int* anyB  = (int*)p;           p += 256;
    u16_t* xh  = (u16_t*)p;         p += 4194304;
    u16_t* xl  = (u16_t*)p;         p += 4194304;
    u16_t* wqh = (u16_t*)p;         p += 1572864;
    u16_t* wql = (u16_t*)p;         p += 1572864;
    u16_t* wph = (u16_t*)p;         p += 524288;
    u16_t* wpl = (u16_t*)p;         p += 524288;
    u16_t* qhp = (u16_t*)p;         p += 4194304;
    u16_t* qlp = (u16_t*)p;         p += 4194304;
    u16_t* khp = (u16_t*)p;         p += 4194304;
    u16_t* klp = (u16_t*)p;         p += 4194304;
    u16_t* vhp = (u16_t*)p;         p += 4194304;
    u16_t* vlp = (u16_t*)p;         p += 4194304;
    u16_t* gbp = (u16_t*)p;         p += 67108864;
    u16_t* aoh = (u16_t*)p;         p += 4194304;
    u16_t* aol = (u16_t*)p;         p += 4194304;

    prep_mask<<<1, 256, 0, stream>>>(msk, mw, anyB);
    presplit<<<12288, 256, 0, stream>>>(x, wqkv, wpj, xh, xl, wqh, wql, wph, wpl);
    gb_pre<<<16384, 256, 0, stream>>>(ef, wep, weg, beg, gbp);
    qkv_mfma<<<dim3(24, 64), 256, 0, stream>>>(xh, xl, wqh, wql,
                                               qhp, qlp, khp, klp, vhp, vlp);
    attn_mfma<<<dim3(Nn / 64, Hh, Bb), 256, 0, stream>>>(qhp, qlp, khp, klp, vhp, vlp,
                                                         gbp, mw, anyB, aoh, aol);
    out_mfma<<<dim3(8, 64), 256, 0, stream>>>(aoh, aol, wph, wpl, bpj, out);
}

// Round 6
// 408.179 us; speedup vs baseline: 1.0673x; 1.0673x over previous
//
#include <hip/hip_runtime.h>

#define Bb 4
#define Nn 1024
#define Dd 512
#define Hh 8
#define Ee 5
#define HDd 64

typedef unsigned int u32_t;
typedef unsigned short u16_t;
typedef unsigned char u8_t;
typedef short s16x8 __attribute__((ext_vector_type(8)));
typedef float f32x4 __attribute__((ext_vector_type(4)));

#define MFMA(a, b, c) __builtin_amdgcn_mfma_f32_16x16x32_bf16((a), (b), (c), 0, 0, 0)

// fp32 -> (hi16 truncated bf16) | (lo16 RN-bf16 of remainder); hi+lo ~= x (rel err ~2^-17)
__device__ __forceinline__ u32_t pack32(float x) {
    u32_t u = __float_as_uint(x);
    u32_t hi = u & 0xffff0000u;
    float rem = x - __uint_as_float(hi);
    u32_t r = __float_as_uint(rem);
    u32_t lo = (r + 0x7fffu + ((r >> 16) & 1u)) >> 16;
    return hi | (lo & 0xffffu);
}

__device__ __forceinline__ u16_t rn16(float x) {
    u32_t u = __float_as_uint(x);
    return (u16_t)((u + 0x7fffu + ((u >> 16) & 1u)) >> 16);
}

__device__ __forceinline__ float bf2f(u16_t v) { return __uint_as_float(((u32_t)v) << 16); }

// 8 packed u32 (two uint4) -> hi bf16x8, lo bf16x8
__device__ __forceinline__ void unpk8(uint4 A, uint4 B, s16x8& h, s16x8& l) {
    union { u16_t u[8]; s16x8 v; } H, L;
    u32_t a[8] = {A.x, A.y, A.z, A.w, B.x, B.y, B.z, B.w};
    #pragma unroll
    for (int i = 0; i < 8; i++) { H.u[i] = (u16_t)(a[i] >> 16); L.u[i] = (u16_t)(a[i] & 0xffffu); }
    h = H.v; l = L.v;
}

// ---------- K0: normalize node_mask -> mw[4096], anyB[4] ----------
__global__ __launch_bounds__(256) void prep_mask(const void* __restrict__ msk,
                                                 int* __restrict__ mw,
                                                 int* __restrict__ anyB) {
    __shared__ int notint;
    __shared__ int ab[Bb];
    const int tid = threadIdx.x;
    if (tid == 0) notint = 0;
    if (tid < Bb) ab[tid] = 0;
    __syncthreads();
    const u32_t* wp = (const u32_t*)msk;
    int bad = 0;
    for (int i = tid; i < 1024; i += 256) bad |= (wp[i] > 1u);
    if (bad) atomicOr(&notint, 1);
    __syncthreads();
    const int isbyte = notint;
    const u8_t* bp = (const u8_t*)msk;
    for (int i = tid; i < Bb * Nn; i += 256) {
        const int v = isbyte ? (bp[i] != 0) : (wp[i] != 0);
        mw[i] = v;
        if (v) atomicOr(&ab[i >> 10], 1);
    }
    __syncthreads();
    if (tid < Bb) anyB[tid] = ab[tid];
}

// ---------- K1: split x, w_qkv, w_proj into bf16 hi/lo ----------
__global__ __launch_bounds__(256) void presplit(const float* __restrict__ x,
                                                const float* __restrict__ wq,
                                                const float* __restrict__ wp,
                                                u16_t* __restrict__ xh, u16_t* __restrict__ xl,
                                                u16_t* __restrict__ wqh, u16_t* __restrict__ wql,
                                                u16_t* __restrict__ wph, u16_t* __restrict__ wpl) {
    const int i = blockIdx.x * 256 + threadIdx.x;  // < 3145728
    const float* src; u16_t *dh, *dl; int off;
    if (i < 2097152)      { src = x;  dh = xh;  dl = xl;  off = i; }
    else if (i < 2883584) { src = wq; dh = wqh; dl = wql; off = i - 2097152; }
    else                  { src = wp; dh = wph; dl = wpl; off = i - 2883584; }
    const u32_t p = pack32(src[off]);
    dh[off] = (u16_t)(p >> 16);
    dl[off] = (u16_t)(p & 0xffffu);
}

// ---------- K2: gb[h][b][i][j] = sigmoid(ef.weg + beg) * (ef.wep), RN bf16 ----------
__global__ __launch_bounds__(256) void gb_pre(const float* __restrict__ ef,
                                              const float* __restrict__ wep,
                                              const float* __restrict__ weg,
                                              const float* __restrict__ beg,
                                              u16_t* __restrict__ gb) {
    const size_t t = (size_t)blockIdx.x * 256 + threadIdx.x;  // < B*N*N
    const float* ep = ef + t * Ee;
    const float e0 = ep[0], e1 = ep[1], e2 = ep[2], e3 = ep[3], e4 = ep[4];
    #pragma unroll
    for (int h = 0; h < Hh; h++) {
        const float bias = fmaf(e0, wep[h*Ee+0], fmaf(e1, wep[h*Ee+1], fmaf(e2, wep[h*Ee+2],
                           fmaf(e3, wep[h*Ee+3], e4 * wep[h*Ee+4]))));
        const float gv = fmaf(e0, weg[h*Ee+0], fmaf(e1, weg[h*Ee+1], fmaf(e2, weg[h*Ee+2],
                         fmaf(e3, weg[h*Ee+3], fmaf(e4, weg[h*Ee+4], beg[h])))));
        const float gate = 1.f / (1.f + __expf(-gv));
        gb[(size_t)h * ((size_t)Bb * Nn * Nn) + t] = rn16(gate * bias);
    }
}

// ---------- K3: qkv GEMM, LDS-staged 64x64 tiles from pre-split inputs ----------
__global__ __launch_bounds__(256) void qkv_mfma(const u16_t* __restrict__ xh, const u16_t* __restrict__ xl,
                                                const u16_t* __restrict__ wh, const u16_t* __restrict__ wl,
                                                u16_t* __restrict__ qh, u16_t* __restrict__ ql,
                                                u16_t* __restrict__ kh, u16_t* __restrict__ kl,
                                                u16_t* __restrict__ vh, u16_t* __restrict__ vl) {
    __shared__ __align__(16) u16_t Ah[64 * 72], Al[64 * 72], Bh[64 * 72], Bl[64 * 72];
    const int tid = threadIdx.x, lane = tid & 63, wv = tid >> 6;
    const int lm = lane & 15, quad = lane >> 4;
    const int mh = wv >> 1, nh = wv & 1;
    const int m0 = blockIdx.y * 64, c0 = blockIdx.x * 64;
    const int row = tid >> 2, co = (tid & 3) * 8;   // u16 chunk offsets: co, co+32

    f32x4 acc[2][2];
    #pragma unroll
    for (int mt = 0; mt < 2; mt++)
        #pragma unroll
        for (int nt = 0; nt < 2; nt++) acc[mt][nt] = {0.f, 0.f, 0.f, 0.f};

    for (int kt = 0; kt < 8; kt++) {
        __syncthreads();
        const size_t ga = (size_t)(m0 + row) * Dd + kt * 64 + co;
        const size_t gb_ = (size_t)(c0 + row) * Dd + kt * 64 + co;
        *(uint4*)&Ah[row * 72 + co]      = *(const uint4*)(xh + ga);
        *(uint4*)&Ah[row * 72 + co + 32] = *(const uint4*)(xh + ga + 32);
        *(uint4*)&Al[row * 72 + co]      = *(const uint4*)(xl + ga);
        *(uint4*)&Al[row * 72 + co + 32] = *(const uint4*)(xl + ga + 32);
        *(uint4*)&Bh[row * 72 + co]      = *(const uint4*)(wh + gb_);
        *(uint4*)&Bh[row * 72 + co + 32] = *(const uint4*)(wh + gb_ + 32);
        *(uint4*)&Bl[row * 72 + co]      = *(const uint4*)(wl + gb_);
        *(uint4*)&Bl[row * 72 + co + 32] = *(const uint4*)(wl + gb_ + 32);
        __syncthreads();
        s16x8 ah[2][2], al[2][2];
        #pragma unroll
        for (int mt = 0; mt < 2; mt++)
            #pragma unroll
            for (int ks = 0; ks < 2; ks++) {
                const int o = (32 * mh + 16 * mt + lm) * 72 + ks * 32 + quad * 8;
                ah[mt][ks] = *(const s16x8*)&Ah[o];
                al[mt][ks] = *(const s16x8*)&Al[o];
            }
        #pragma unroll
        for (int nt = 0; nt < 2; nt++)
            #pragma unroll
            for (int ks = 0; ks < 2; ks++) {
                const int o = (32 * nh + 16 * nt + lm) * 72 + ks * 32 + quad * 8;
                s16x8 bh = *(const s16x8*)&Bh[o];
                s16x8 bl = *(const s16x8*)&Bl[o];
                #pragma unroll
                for (int mt = 0; mt < 2; mt++) {
                    acc[mt][nt] = MFMA(ah[mt][ks], bh, acc[mt][nt]);
                    acc[mt][nt] = MFMA(ah[mt][ks], bl, acc[mt][nt]);
                    acc[mt][nt] = MFMA(al[mt][ks], bh, acc[mt][nt]);
                }
            }
    }
    #pragma unroll
    for (int nt = 0; nt < 2; nt++) {
        const int c = c0 + 32 * nh + 16 * nt + lm;
        const int s = c >> 9, hd = c & 511, h = hd >> 6, d = hd & 63;
        u16_t* dh = (s == 0) ? qh : (s == 1) ? kh : vh;
        u16_t* dl = (s == 0) ? ql : (s == 1) ? kl : vl;
        #pragma unroll
        for (int mt = 0; mt < 2; mt++)
            #pragma unroll
            for (int r = 0; r < 4; r++) {
                const int m = m0 + 32 * mh + 16 * mt + 4 * quad + r;
                const int b = m >> 10, n = m & (Nn - 1);
                const size_t o = (((size_t)b * Hh + h) * Nn + n) * HDd + d;
                const u32_t p = pack32(acc[mt][nt][r]);
                dh[o] = (u16_t)(p >> 16);
                dl[o] = (u16_t)(p & 0xffffu);
            }
    }
}

// ---------- K4: V[b][h][n][d] -> VT[b][h][d][n] (hi and lo) ----------
__global__ __launch_bounds__(256) void vt_trans(const u16_t* __restrict__ vh, const u16_t* __restrict__ vl,
                                                u16_t* __restrict__ vth, u16_t* __restrict__ vtl) {
    __shared__ __align__(16) u16_t Th[64 * 72], Tl[64 * 72];
    const int tid = threadIdx.x;
    const size_t plane = (size_t)blockIdx.y * (Nn * HDd);
    const int n0 = blockIdx.x * 64;
    const int row = tid >> 2, co = (tid & 3) * 8;
    {
        const size_t g = plane + (size_t)(n0 + row) * HDd + co;
        *(uint4*)&Th[row * 72 + co]      = *(const uint4*)(vh + g);
        *(uint4*)&Th[row * 72 + co + 32] = *(const uint4*)(vh + g + 32);
        *(uint4*)&Tl[row * 72 + co]      = *(const uint4*)(vl + g);
        *(uint4*)&Tl[row * 72 + co + 32] = *(const uint4*)(vl + g + 32);
    }
    __syncthreads();
    const int d = tid >> 2, nc = (tid & 3) * 16;     // 16 n per chunk
    union { u16_t u[8]; uint4 v; } oh, ol;
    #pragma unroll 2
    for (int half = 0; half < 2; half++) {
        #pragma unroll
        for (int t = 0; t < 8; t++) {
            oh.u[t] = Th[(nc + half * 8 + t) * 72 + d];
            ol.u[t] = Tl[(nc + half * 8 + t) * 72 + d];
        }
        const size_t g = plane + (size_t)d * Nn + n0 + nc + half * 8;
        *(uint4*)(vth + g) = oh.v;
        *(uint4*)(vtl + g) = ol.v;
    }
}

// ---------- K5: flash attention, barrier-free jt loop ----------
__global__ __launch_bounds__(256) void attn_mfma(const u16_t* __restrict__ qh, const u16_t* __restrict__ ql,
                                                 const u16_t* __restrict__ kh, const u16_t* __restrict__ kl,
                                                 const u16_t* __restrict__ vth, const u16_t* __restrict__ vtl,
                                                 const u16_t* __restrict__ gb,
                                                 const int* __restrict__ mw,
                                                 const int* __restrict__ anyB,
                                                 u16_t* __restrict__ aoh, u16_t* __restrict__ aol) {
    __shared__ __align__(16) u32_t Pk[4][16 * 68];   // wave-private packed P (17408 B)

    const int tid = threadIdx.x;
    const int wv = tid >> 6, lane = tid & 63, lm = lane & 15, quad = lane >> 4;
    const int i0 = blockIdx.x * 64;
    const int h  = blockIdx.y;
    const int b  = blockIdx.z;

    const size_t plane = (((size_t)b * Hh + h) * Nn) * HDd;
    const u16_t* khp = kh + plane;
    const u16_t* klp = kl + plane;
    const u16_t* vthp = vth + plane;   // [d][n]
    const u16_t* vtlp = vtl + plane;
    const u16_t* gbq = gb + (((size_t)h * Bb + b) << 20);
    const int* mwB = mw + b * Nn;
    u32_t* Pw = &Pk[wv][0];

    // Q A-frags once, direct from global
    s16x8 qfh[2], qfl[2];
    {
        const size_t row = plane + (size_t)(i0 + 16 * wv + lm) * HDd + quad * 8;
        #pragma unroll
        for (int ks = 0; ks < 2; ks++) {
            qfh[ks] = *(const s16x8*)(qh + row + ks * 32);
            qfl[ks] = *(const s16x8*)(ql + row + ks * 32);
        }
    }

    const int anyb = anyB[b];
    int rv[4];
    float m_[4], l_[4];
    f32x4 accO[4];
    #pragma unroll
    for (int r = 0; r < 4; r++) {
        rv[r] = anyb && mwB[i0 + 16 * wv + 4 * quad + r];
        m_[r] = -1e30f; l_[r] = 0.f;
    }
    #pragma unroll
    for (int dn = 0; dn < 4; dn++) accO[dn] = {0.f, 0.f, 0.f, 0.f};

    for (int jt = 0; jt < Nn / 64; jt++) {
        const int j0 = jt * 64;

        // ---- QK^T: K B-frags direct from global ----
        f32x4 S[4];
        #pragma unroll
        for (int jn = 0; jn < 4; jn++) {
            const size_t row = (size_t)(j0 + 16 * jn + lm) * HDd + quad * 8;
            f32x4 s = {0.f, 0.f, 0.f, 0.f};
            #pragma unroll
            for (int ks = 0; ks < 2; ks++) {
                s16x8 bh = *(const s16x8*)(khp + row + ks * 32);
                s16x8 bl = *(const s16x8*)(klp + row + ks * 32);
                s = MFMA(qfh[ks], bh, s);
                s = MFMA(qfh[ks], bl, s);
                s = MFMA(qfl[ks], bh, s);
            }
            S[jn] = s;
        }

        int mj[4];
        #pragma unroll
        for (int jn = 0; jn < 4; jn++) mj[jn] = mwB[j0 + 16 * jn + lm];

        // ---- scores + mask + online softmax; P -> wave-private LDS ----
        #pragma unroll
        for (int r = 0; r < 4; r++) {
            const int i = i0 + 16 * wv + 4 * quad + r;
            float sv[4];
            #pragma unroll
            for (int jn = 0; jn < 4; jn++) {
                if (!rv[r]) {
                    sv[jn] = 0.f;
                } else if (!mj[jn]) {
                    sv[jn] = -1e30f;
                } else {
                    const float g = bf2f(gbq[(size_t)i * Nn + j0 + 16 * jn + lm]);
                    sv[jn] = fmaf(S[jn][r], 0.125f, g);
                }
            }
            float tmax = fmaxf(fmaxf(sv[0], sv[1]), fmaxf(sv[2], sv[3]));
            tmax = fmaxf(tmax, __shfl_xor(tmax, 1));
            tmax = fmaxf(tmax, __shfl_xor(tmax, 2));
            tmax = fmaxf(tmax, __shfl_xor(tmax, 4));
            tmax = fmaxf(tmax, __shfl_xor(tmax, 8));
            const float mnew = fmaxf(m_[r], tmax);
            const float alpha = __expf(m_[r] - mnew);
            float p[4], ps = 0.f;
            #pragma unroll
            for (int jn = 0; jn < 4; jn++) { p[jn] = __expf(sv[jn] - mnew); ps += p[jn]; }
            ps += __shfl_xor(ps, 1);
            ps += __shfl_xor(ps, 2);
            ps += __shfl_xor(ps, 4);
            ps += __shfl_xor(ps, 8);
            m_[r] = mnew;
            l_[r] = l_[r] * alpha + ps;
            #pragma unroll
            for (int dn = 0; dn < 4; dn++) accO[dn][r] *= alpha;
            #pragma unroll
            for (int jn = 0; jn < 4; jn++)
                Pw[(4 * quad + r) * 68 + 16 * jn + lm] = pack32(p[jn]);
        }

        // ---- PV: P A-frags from own LDS (wave-private, no barrier); V from global VT ----
        s16x8 ph[2], pl[2];
        #pragma unroll
        for (int ks2 = 0; ks2 < 2; ks2++) {
            const int off = lm * 68 + ks2 * 32 + quad * 8;
            uint4 A = *(const uint4*)&Pw[off];
            uint4 B = *(const uint4*)&Pw[off + 4];
            unpk8(A, B, ph[ks2], pl[ks2]);
        }
        #pragma unroll
        for (int dn = 0; dn < 4; dn++) {
            const size_t row = (size_t)(16 * dn + lm) * Nn + j0;
            f32x4 c = accO[dn];
            #pragma unroll
            for (int ks2 = 0; ks2 < 2; ks2++) {
                s16x8 vvh = *(const s16x8*)(vthp + row + ks2 * 32 + quad * 8);
                s16x8 vvl = *(const s16x8*)(vtlp + row + ks2 * 32 + quad * 8);
                c = MFMA(ph[ks2], vvh, c);
                c = MFMA(ph[ks2], vvl, c);
                c = MFMA(pl[ks2], vvh, c);
            }
            accO[dn] = c;
        }
    }

    #pragma unroll
    for (int r = 0; r < 4; r++) {
        const int i = i0 + 16 * wv + 4 * quad + r;
        const float inv = 1.f / l_[r];
        #pragma unroll
        for (int dn = 0; dn < 4; dn++) {
            const size_t o = (size_t)(b * Nn + i) * Dd + h * HDd + 16 * dn + lm;
            const u32_t p = pack32(accO[dn][r] * inv);
            aoh[o] = (u16_t)(p >> 16);
            aol[o] = (u16_t)(p & 0xffffu);
        }
    }
}

// ---------- K6: out = ao @ w_proj^T + bias, LDS-staged ----------
__global__ __launch_bounds__(256) void out_mfma(const u16_t* __restrict__ ah_, const u16_t* __restrict__ al_,
                                                const u16_t* __restrict__ wh, const u16_t* __restrict__ wl,
                                                const float* __restrict__ bias,
                                                float* __restrict__ out) {
    __shared__ __align__(16) u16_t Ah[64 * 72], Al[64 * 72], Bh[64 * 72], Bl[64 * 72];
    const int tid = threadIdx.x, lane = tid & 63, wv = tid >> 6;
    const int lm = lane & 15, quad = lane >> 4;
    const int mh = wv >> 1, nh = wv & 1;
    const int m0 = blockIdx.y * 64, c0 = blockIdx.x * 64;
    const int row = tid >> 2, co = (tid & 3) * 8;

    f32x4 acc[2][2];
    #pragma unroll
    for (int mt = 0; mt < 2; mt++)
        #pragma unroll
        for (int nt = 0; nt < 2; nt++) acc[mt][nt] = {0.f, 0.f, 0.f, 0.f};

    for (int kt = 0; kt < 8; kt++) {
        __syncthreads();
        const size_t ga = (size_t)(m0 + row) * Dd + kt * 64 + co;
        const size_t gb_ = (size_t)(c0 + row) * Dd + kt * 64 + co;
        *(uint4*)&Ah[row * 72 + co]      = *(const uint4*)(ah_ + ga);
        *(uint4*)&Ah[row * 72 + co + 32] = *(const uint4*)(ah_ + ga + 32);
        *(uint4*)&Al[row * 72 + co]      = *(const uint4*)(al_ + ga);
        *(uint4*)&Al[row * 72 + co + 32] = *(const uint4*)(al_ + ga + 32);
        *(uint4*)&Bh[row * 72 + co]      = *(const uint4*)(wh + gb_);
        *(uint4*)&Bh[row * 72 + co + 32] = *(const uint4*)(wh + gb_ + 32);
        *(uint4*)&Bl[row * 72 + co]      = *(const uint4*)(wl + gb_);
        *(uint4*)&Bl[row * 72 + co + 32] = *(const uint4*)(wl + gb_ + 32);
        __syncthreads();
        s16x8 ah[2][2], al[2][2];
        #pragma unroll
        for (int mt = 0; mt < 2; mt++)
            #pragma unroll
            for (int ks = 0; ks < 2; ks++) {
                const int o = (32 * mh + 16 * mt + lm) * 72 + ks * 32 + quad * 8;
                ah[mt][ks] = *(const s16x8*)&Ah[o];
                al[mt][ks] = *(const s16x8*)&Al[o];
            }
        #pragma unroll
        for (int nt = 0; nt < 2; nt++)
            #pragma unroll
            for (int ks = 0; ks < 2; ks++) {
                const int o = (32 * nh + 16 * nt + lm) * 72 + ks * 32 + quad * 8;
                s16x8 bh = *(const s16x8*)&Bh[o];
                s16x8 bl = *(const s16x8*)&Bl[o];
                #pragma unroll
                for (int mt = 0; mt < 2; mt++) {
                    acc[mt][nt] = MFMA(ah[mt][ks], bh, acc[mt][nt]);
                    acc[mt][nt] = MFMA(ah[mt][ks], bl, acc[mt][nt]);
                    acc[mt][nt] = MFMA(al[mt][ks], bh, acc[mt][nt]);
                }
            }
    }
    #pragma unroll
    for (int nt = 0; nt < 2; nt++) {
        const int c = c0 + 32 * nh + 16 * nt + lm;
        const float bc = bias[c];
        #pragma unroll
        for (int mt = 0; mt < 2; mt++)
            #pragma unroll
            for (int r = 0; r < 4; r++) {
                const int m = m0 + 32 * mh + 16 * mt + 4 * quad + r;
                out[(size_t)m * Dd + c] = acc[mt][nt][r] + bc;
            }
    }
}

extern "C" void kernel_launch(void* const* d_in, const int* in_sizes, int n_in,
                              void* d_out, int out_size, void* d_ws, size_t ws_size,
                              hipStream_t stream) {
    const float* x    = (const float*)d_in[0];
    const float* ef   = (const float*)d_in[1];
    const void*  msk  = d_in[2];
    const float* wqkv = (const float*)d_in[3];
    const float* wep  = (const float*)d_in[4];
    const float* weg  = (const float*)d_in[5];
    const float* beg  = (const float*)d_in[6];
    const float* wpj  = (const float*)d_in[7];
    const float* bpj  = (const float*)d_in[8];
    float* out = (float*)d_out;

    u8_t* p = (u8_t*)d_ws;
    int* mw    = (int*)p;           p += 16384;
    int* anyB  = (int*)p;           p += 256;
    u16_t* xh  = (u16_t*)p;         p += 4194304;
    u16_t* xl  = (u16_t*)p;         p += 4194304;
    u16_t* wqh = (u16_t*)p;         p += 1572864;
    u16_t* wql = (u16_t*)p;         p += 1572864;
    u16_t* wph = (u16_t*)p;         p += 524288;
    u16_t* wpl = (u16_t*)p;         p += 524288;
    u16_t* qhp = (u16_t*)p;         p += 4194304;
    u16_t* qlp = (u16_t*)p;         p += 4194304;
    u16_t* khp = (u16_t*)p;         p += 4194304;
    u16_t* klp = (u16_t*)p;         p += 4194304;
    u16_t* vhp = (u16_t*)p;         p += 4194304;
    u16_t* vlp = (u16_t*)p;         p += 4194304;
    u16_t* vth = (u16_t*)p;         p += 4194304;
    u16_t* vtl = (u16_t*)p;         p += 4194304;
    u16_t* gbp = (u16_t*)p;         p += 67108864;
    u16_t* aoh = (u16_t*)p;         p += 4194304;
    u16_t* aol = (u16_t*)p;         p += 4194304;

    prep_mask<<<1, 256, 0, stream>>>(msk, mw, anyB);
    presplit<<<12288, 256, 0, stream>>>(x, wqkv, wpj, xh, xl, wqh, wql, wph, wpl);
    gb_pre<<<16384, 256, 0, stream>>>(ef, wep, weg, beg, gbp);
    qkv_mfma<<<dim3(24, 64), 256, 0, stream>>>(xh, xl, wqh, wql,
                                               qhp, qlp, khp, klp, vhp, vlp);
    vt_trans<<<dim3(16, Bb * Hh), 256, 0, stream>>>(vhp, vlp, vth, vtl);
    attn_mfma<<<dim3(Nn / 64, Hh, Bb), 256, 0, stream>>>(qhp, qlp, khp, klp, vth, vtl,
                                                         gbp, mw, anyB, aoh, aol);
    out_mfma<<<dim3(8, 64), 256, 0, stream>>>(aoh, aol, wph, wpl, bpj, out);
}

// Round 7
// 402.235 us; speedup vs baseline: 1.0831x; 1.0148x over previous
//
#include <hip/hip_runtime.h>

#define Bb 4
#define Nn 1024
#define Dd 512
#define Hh 8
#define Ee 5
#define HDd 64

typedef unsigned int u32_t;
typedef unsigned short u16_t;
typedef unsigned char u8_t;
typedef short s16x8 __attribute__((ext_vector_type(8)));
typedef float f32x4 __attribute__((ext_vector_type(4)));

#define MFMA(a, b, c) __builtin_amdgcn_mfma_f32_16x16x32_bf16((a), (b), (c), 0, 0, 0)

// fp32 -> (hi16 truncated bf16) | (lo16 RN-bf16 of remainder); hi+lo ~= x (rel err ~2^-17)
__device__ __forceinline__ u32_t pack32(float x) {
    u32_t u = __float_as_uint(x);
    u32_t hi = u & 0xffff0000u;
    float rem = x - __uint_as_float(hi);
    u32_t r = __float_as_uint(rem);
    u32_t lo = (r + 0x7fffu + ((r >> 16) & 1u)) >> 16;
    return hi | (lo & 0xffffu);
}

__device__ __forceinline__ u16_t rn16(float x) {
    u32_t u = __float_as_uint(x);
    return (u16_t)((u + 0x7fffu + ((u >> 16) & 1u)) >> 16);
}

__device__ __forceinline__ float bf2f(u16_t v) { return __uint_as_float(((u32_t)v) << 16); }

// 8 packed u32 (two uint4) -> hi bf16x8, lo bf16x8
__device__ __forceinline__ void unpk8(uint4 A, uint4 B, s16x8& h, s16x8& l) {
    union { u16_t u[8]; s16x8 v; } H, L;
    u32_t a[8] = {A.x, A.y, A.z, A.w, B.x, B.y, B.z, B.w};
    #pragma unroll
    for (int i = 0; i < 8; i++) { H.u[i] = (u16_t)(a[i] >> 16); L.u[i] = (u16_t)(a[i] & 0xffffu); }
    h = H.v; l = L.v;
}

// ---------- K0: normalize node_mask -> mw[4096], anyB[4] ----------
__global__ __launch_bounds__(256) void prep_mask(const void* __restrict__ msk,
                                                 int* __restrict__ mw,
                                                 int* __restrict__ anyB) {
    __shared__ int notint;
    __shared__ int ab[Bb];
    const int tid = threadIdx.x;
    if (tid == 0) notint = 0;
    if (tid < Bb) ab[tid] = 0;
    __syncthreads();
    const u32_t* wp = (const u32_t*)msk;
    int bad = 0;
    for (int i = tid; i < 1024; i += 256) bad |= (wp[i] > 1u);
    if (bad) atomicOr(&notint, 1);
    __syncthreads();
    const int isbyte = notint;
    const u8_t* bp = (const u8_t*)msk;
    for (int i = tid; i < Bb * Nn; i += 256) {
        const int v = isbyte ? (bp[i] != 0) : (wp[i] != 0);
        mw[i] = v;
        if (v) atomicOr(&ab[i >> 10], 1);
    }
    __syncthreads();
    if (tid < Bb) anyB[tid] = ab[tid];
}

// ---------- K1: split x, w_qkv, w_proj into bf16 hi/lo ----------
__global__ __launch_bounds__(256) void presplit(const float* __restrict__ x,
                                                const float* __restrict__ wq,
                                                const float* __restrict__ wp,
                                                u16_t* __restrict__ xh, u16_t* __restrict__ xl,
                                                u16_t* __restrict__ wqh, u16_t* __restrict__ wql,
                                                u16_t* __restrict__ wph, u16_t* __restrict__ wpl) {
    const int i = blockIdx.x * 256 + threadIdx.x;  // < 3145728
    const float* src; u16_t *dh, *dl; int off;
    if (i < 2097152)      { src = x;  dh = xh;  dl = xl;  off = i; }
    else if (i < 2883584) { src = wq; dh = wqh; dl = wql; off = i - 2097152; }
    else                  { src = wp; dh = wph; dl = wpl; off = i - 2883584; }
    const u32_t p = pack32(src[off]);
    dh[off] = (u16_t)(p >> 16);
    dl[off] = (u16_t)(p & 0xffffu);
}

// ---------- K2: gb[h][b][i][j] = sigmoid(ef.weg+beg)*(ef.wep), RN bf16; 4 elems/thread ----------
__global__ __launch_bounds__(256) void gb_pre(const float* __restrict__ ef,
                                              const float* __restrict__ wep,
                                              const float* __restrict__ weg,
                                              const float* __restrict__ beg,
                                              u16_t* __restrict__ gb) {
    const size_t t0 = ((size_t)blockIdx.x * 256 + threadIdx.x) * 4;  // < B*N*N
    const float4* e4 = (const float4*)(ef + t0 * 5);
    const float4 va = e4[0], vb = e4[1], vc = e4[2], vd = e4[3], ve = e4[4];
    const float E[4][5] = {{va.x, va.y, va.z, va.w, vb.x},
                           {vb.y, vb.z, vb.w, vc.x, vc.y},
                           {vc.z, vc.w, vd.x, vd.y, vd.z},
                           {vd.w, ve.x, ve.y, ve.z, ve.w}};
    #pragma unroll
    for (int h = 0; h < Hh; h++) {
        const float p0 = wep[h*Ee+0], p1 = wep[h*Ee+1], p2 = wep[h*Ee+2],
                    p3 = wep[h*Ee+3], p4 = wep[h*Ee+4];
        const float g0 = weg[h*Ee+0], g1 = weg[h*Ee+1], g2 = weg[h*Ee+2],
                    g3 = weg[h*Ee+3], g4 = weg[h*Ee+4];
        const float bg = beg[h];
        u16_t o[4];
        #pragma unroll
        for (int tt = 0; tt < 4; tt++) {
            const float bias = fmaf(E[tt][0], p0, fmaf(E[tt][1], p1, fmaf(E[tt][2], p2,
                               fmaf(E[tt][3], p3, E[tt][4] * p4))));
            const float gv = fmaf(E[tt][0], g0, fmaf(E[tt][1], g1, fmaf(E[tt][2], g2,
                             fmaf(E[tt][3], g3, fmaf(E[tt][4], g4, bg)))));
            const float gate = 1.f / (1.f + __expf(-gv));
            o[tt] = rn16(gate * bias);
        }
        uint2 w;
        w.x = (u32_t)o[0] | ((u32_t)o[1] << 16);
        w.y = (u32_t)o[2] | ((u32_t)o[3] << 16);
        *(uint2*)(gb + (size_t)h * ((size_t)Bb * Nn * Nn) + t0) = w;
    }
}

// ---------- K3: qkv GEMM, LDS-staged 64x64 tiles from pre-split inputs ----------
__global__ __launch_bounds__(256) void qkv_mfma(const u16_t* __restrict__ xh, const u16_t* __restrict__ xl,
                                                const u16_t* __restrict__ wh, const u16_t* __restrict__ wl,
                                                u16_t* __restrict__ qh, u16_t* __restrict__ ql,
                                                u16_t* __restrict__ kh, u16_t* __restrict__ kl,
                                                u16_t* __restrict__ vh, u16_t* __restrict__ vl) {
    __shared__ __align__(16) u16_t Ah[64 * 72], Al[64 * 72], Bh[64 * 72], Bl[64 * 72];
    const int tid = threadIdx.x, lane = tid & 63, wv = tid >> 6;
    const int lm = lane & 15, quad = lane >> 4;
    const int mh = wv >> 1, nh = wv & 1;
    const int m0 = blockIdx.y * 64, c0 = blockIdx.x * 64;
    const int row = tid >> 2, co = (tid & 3) * 8;

    f32x4 acc[2][2];
    #pragma unroll
    for (int mt = 0; mt < 2; mt++)
        #pragma unroll
        for (int nt = 0; nt < 2; nt++) acc[mt][nt] = {0.f, 0.f, 0.f, 0.f};

    for (int kt = 0; kt < 8; kt++) {
        __syncthreads();
        const size_t ga = (size_t)(m0 + row) * Dd + kt * 64 + co;
        const size_t gb_ = (size_t)(c0 + row) * Dd + kt * 64 + co;
        *(uint4*)&Ah[row * 72 + co]      = *(const uint4*)(xh + ga);
        *(uint4*)&Ah[row * 72 + co + 32] = *(const uint4*)(xh + ga + 32);
        *(uint4*)&Al[row * 72 + co]      = *(const uint4*)(xl + ga);
        *(uint4*)&Al[row * 72 + co + 32] = *(const uint4*)(xl + ga + 32);
        *(uint4*)&Bh[row * 72 + co]      = *(const uint4*)(wh + gb_);
        *(uint4*)&Bh[row * 72 + co + 32] = *(const uint4*)(wh + gb_ + 32);
        *(uint4*)&Bl[row * 72 + co]      = *(const uint4*)(wl + gb_);
        *(uint4*)&Bl[row * 72 + co + 32] = *(const uint4*)(wl + gb_ + 32);
        __syncthreads();
        s16x8 ah[2][2], al[2][2];
        #pragma unroll
        for (int mt = 0; mt < 2; mt++)
            #pragma unroll
            for (int ks = 0; ks < 2; ks++) {
                const int o = (32 * mh + 16 * mt + lm) * 72 + ks * 32 + quad * 8;
                ah[mt][ks] = *(const s16x8*)&Ah[o];
                al[mt][ks] = *(const s16x8*)&Al[o];
            }
        #pragma unroll
        for (int nt = 0; nt < 2; nt++)
            #pragma unroll
            for (int ks = 0; ks < 2; ks++) {
                const int o = (32 * nh + 16 * nt + lm) * 72 + ks * 32 + quad * 8;
                s16x8 bh = *(const s16x8*)&Bh[o];
                s16x8 bl = *(const s16x8*)&Bl[o];
                #pragma unroll
                for (int mt = 0; mt < 2; mt++) {
                    acc[mt][nt] = MFMA(ah[mt][ks], bh, acc[mt][nt]);
                    acc[mt][nt] = MFMA(ah[mt][ks], bl, acc[mt][nt]);
                    acc[mt][nt] = MFMA(al[mt][ks], bh, acc[mt][nt]);
                }
            }
    }
    #pragma unroll
    for (int nt = 0; nt < 2; nt++) {
        const int c = c0 + 32 * nh + 16 * nt + lm;
        const int s = c >> 9, hd = c & 511, h = hd >> 6, d = hd & 63;
        u16_t* dh = (s == 0) ? qh : (s == 1) ? kh : vh;
        u16_t* dl = (s == 0) ? ql : (s == 1) ? kl : vl;
        #pragma unroll
        for (int mt = 0; mt < 2; mt++)
            #pragma unroll
            for (int r = 0; r < 4; r++) {
                const int m = m0 + 32 * mh + 16 * mt + 4 * quad + r;
                const int b = m >> 10, n = m & (Nn - 1);
                const size_t o = (((size_t)b * Hh + h) * Nn + n) * HDd + d;
                const u32_t p = pack32(acc[mt][nt][r]);
                dh[o] = (u16_t)(p >> 16);
                dl[o] = (u16_t)(p & 0xffffu);
            }
    }
}

// ---------- K4: V[b][h][n][d] -> VT[b][h][d][n] (hi and lo) ----------
__global__ __launch_bounds__(256) void vt_trans(const u16_t* __restrict__ vh, const u16_t* __restrict__ vl,
                                                u16_t* __restrict__ vth, u16_t* __restrict__ vtl) {
    __shared__ __align__(16) u16_t Th[64 * 72], Tl[64 * 72];
    const int tid = threadIdx.x;
    const size_t plane = (size_t)blockIdx.y * (Nn * HDd);
    const int n0 = blockIdx.x * 64;
    const int row = tid >> 2, co = (tid & 3) * 8;
    {
        const size_t g = plane + (size_t)(n0 + row) * HDd + co;
        *(uint4*)&Th[row * 72 + co]      = *(const uint4*)(vh + g);
        *(uint4*)&Th[row * 72 + co + 32] = *(const uint4*)(vh + g + 32);
        *(uint4*)&Tl[row * 72 + co]      = *(const uint4*)(vl + g);
        *(uint4*)&Tl[row * 72 + co + 32] = *(const uint4*)(vl + g + 32);
    }
    __syncthreads();
    const int d = tid >> 2, nc = (tid & 3) * 16;
    union { u16_t u[8]; uint4 v; } oh, ol;
    #pragma unroll 2
    for (int half = 0; half < 2; half++) {
        #pragma unroll
        for (int t = 0; t < 8; t++) {
            oh.u[t] = Th[(nc + half * 8 + t) * 72 + d];
            ol.u[t] = Tl[(nc + half * 8 + t) * 72 + d];
        }
        const size_t g = plane + (size_t)d * Nn + n0 + nc + half * 8;
        *(uint4*)(vth + g) = oh.v;
        *(uint4*)(vtl + g) = ol.v;
    }
}

// ---------- K5: flash attention, intra-block j-split (wave w owns j-quarter), LDS merge ----------
__global__ __launch_bounds__(256) void attn_mfma(const u16_t* __restrict__ qh, const u16_t* __restrict__ ql,
                                                 const u16_t* __restrict__ kh, const u16_t* __restrict__ kl,
                                                 const u16_t* __restrict__ vth, const u16_t* __restrict__ vtl,
                                                 const u16_t* __restrict__ gb,
                                                 const int* __restrict__ mw,
                                                 const int* __restrict__ anyB,
                                                 u16_t* __restrict__ aoh, u16_t* __restrict__ aol) {
    // Pk (17408 B) holds wave-private packed P during the loop, then is aliased
    // by the combine buffers (Ob 16384 B + ml 512 B).
    __shared__ __align__(16) u32_t Pk[4][16 * 68];

    const int tid = threadIdx.x;
    const int wv = tid >> 6, lane = tid & 63, lm = lane & 15, quad = lane >> 4;
    const int i0 = blockIdx.x * 16;   // 16 i-rows per block; all 4 waves share them
    const int h  = blockIdx.y;
    const int b  = blockIdx.z;

    const size_t plane = (((size_t)b * Hh + h) * Nn) * HDd;
    const u16_t* khp = kh + plane;
    const u16_t* klp = kl + plane;
    const u16_t* vthp = vth + plane;   // [d][n]
    const u16_t* vtlp = vtl + plane;
    const u16_t* gbq = gb + (((size_t)h * Bb + b) << 20);
    const int* mwB = mw + b * Nn;
    u32_t* Pw = &Pk[wv][0];

    // Q A-frags once: row = i0 + lm (same for all waves)
    s16x8 qfh[2], qfl[2];
    {
        const size_t row = plane + (size_t)(i0 + lm) * HDd + quad * 8;
        #pragma unroll
        for (int ks = 0; ks < 2; ks++) {
            qfh[ks] = *(const s16x8*)(qh + row + ks * 32);
            qfl[ks] = *(const s16x8*)(ql + row + ks * 32);
        }
    }

    const int anyb = anyB[b];
    int rv[4];
    float m_[4], l_[4];
    f32x4 accO[4];
    #pragma unroll
    for (int r = 0; r < 4; r++) {
        rv[r] = anyb && mwB[i0 + 4 * quad + r];
        m_[r] = -1e30f; l_[r] = 0.f;
    }
    #pragma unroll
    for (int dn = 0; dn < 4; dn++) accO[dn] = {0.f, 0.f, 0.f, 0.f};

    // wave wv processes j in [256*wv, 256*wv+256)
    for (int jt = 4 * wv; jt < 4 * wv + 4; jt++) {
        const int j0 = jt * 64;

        // ---- QK^T: K B-frags direct from global ----
        f32x4 S[4];
        #pragma unroll
        for (int jn = 0; jn < 4; jn++) {
            const size_t row = (size_t)(j0 + 16 * jn + lm) * HDd + quad * 8;
            f32x4 s = {0.f, 0.f, 0.f, 0.f};
            #pragma unroll
            for (int ks = 0; ks < 2; ks++) {
                s16x8 bh = *(const s16x8*)(khp + row + ks * 32);
                s16x8 bl = *(const s16x8*)(klp + row + ks * 32);
                s = MFMA(qfh[ks], bh, s);
                s = MFMA(qfh[ks], bl, s);
                s = MFMA(qfl[ks], bh, s);
            }
            S[jn] = s;
        }

        int mj[4];
        #pragma unroll
        for (int jn = 0; jn < 4; jn++) mj[jn] = mwB[j0 + 16 * jn + lm];

        // ---- scores + mask + online softmax; P -> wave-private LDS ----
        #pragma unroll
        for (int r = 0; r < 4; r++) {
            const int i = i0 + 4 * quad + r;
            float sv[4];
            #pragma unroll
            for (int jn = 0; jn < 4; jn++) {
                if (!rv[r]) {
                    sv[jn] = 0.f;
                } else if (!mj[jn]) {
                    sv[jn] = -1e30f;
                } else {
                    const float g = bf2f(gbq[(size_t)i * Nn + j0 + 16 * jn + lm]);
                    sv[jn] = fmaf(S[jn][r], 0.125f, g);
                }
            }
            float tmax = fmaxf(fmaxf(sv[0], sv[1]), fmaxf(sv[2], sv[3]));
            tmax = fmaxf(tmax, __shfl_xor(tmax, 1));
            tmax = fmaxf(tmax, __shfl_xor(tmax, 2));
            tmax = fmaxf(tmax, __shfl_xor(tmax, 4));
            tmax = fmaxf(tmax, __shfl_xor(tmax, 8));
            const float mnew = fmaxf(m_[r], tmax);
            const float alpha = __expf(m_[r] - mnew);
            float p[4], ps = 0.f;
            #pragma unroll
            for (int jn = 0; jn < 4; jn++) { p[jn] = __expf(sv[jn] - mnew); ps += p[jn]; }
            ps += __shfl_xor(ps, 1);
            ps += __shfl_xor(ps, 2);
            ps += __shfl_xor(ps, 4);
            ps += __shfl_xor(ps, 8);
            m_[r] = mnew;
            l_[r] = l_[r] * alpha + ps;
            #pragma unroll
            for (int dn = 0; dn < 4; dn++) accO[dn][r] *= alpha;
            #pragma unroll
            for (int jn = 0; jn < 4; jn++)
                Pw[(4 * quad + r) * 68 + 16 * jn + lm] = pack32(p[jn]);
        }

        // ---- PV: P A-frags from own LDS (wave-private); V B-frags from global VT ----
        s16x8 ph[2], pl[2];
        #pragma unroll
        for (int ks2 = 0; ks2 < 2; ks2++) {
            const int off = lm * 68 + ks2 * 32 + quad * 8;
            uint4 A = *(const uint4*)&Pw[off];
            uint4 B = *(const uint4*)&Pw[off + 4];
            unpk8(A, B, ph[ks2], pl[ks2]);
        }
        #pragma unroll
        for (int dn = 0; dn < 4; dn++) {
            const size_t row = (size_t)(16 * dn + lm) * Nn + j0;
            f32x4 c = accO[dn];
            #pragma unroll
            for (int ks2 = 0; ks2 < 2; ks2++) {
                s16x8 vvh = *(const s16x8*)(vthp + row + ks2 * 32 + quad * 8);
                s16x8 vvl = *(const s16x8*)(vtlp + row + ks2 * 32 + quad * 8);
                c = MFMA(ph[ks2], vvh, c);
                c = MFMA(ph[ks2], vvl, c);
                c = MFMA(pl[ks2], vvh, c);
            }
            accO[dn] = c;
        }
    }

    // ---- combine the 4 waves' partials (Ob/ml alias Pk) ----
    __syncthreads();   // all waves done reading their Pk region
    f32x4* Ob4 = (f32x4*)&Pk[0][0];        // [(w*4+dn)*64 + lane]
    float* ml = (float*)&Pk[0][0] + 4096;  // [w*32 + {0:m,16:l} + row]
    #pragma unroll
    for (int dn = 0; dn < 4; dn++) Ob4[(wv * 4 + dn) * 64 + lane] = accO[dn];
    if (lm == 0) {
        #pragma unroll
        for (int r = 0; r < 4; r++) {
            ml[wv * 32 + 4 * quad + r]      = m_[r];
            ml[wv * 32 + 16 + 4 * quad + r] = l_[r];
        }
    }
    __syncthreads();

    float coef[4][4], invL[4];
    #pragma unroll
    for (int r = 0; r < 4; r++) {
        const int row = 4 * quad + r;
        float M = -1e30f;
        #pragma unroll
        for (int w = 0; w < 4; w++) M = fmaxf(M, ml[w * 32 + row]);
        float L = 0.f;
        #pragma unroll
        for (int w = 0; w < 4; w++) {
            const float cw = __expf(ml[w * 32 + row] - M);
            coef[w][r] = cw;
            L = fmaf(cw, ml[w * 32 + 16 + row], L);
        }
        invL[r] = 1.f / L;
    }
    // each wave finalizes and writes only its dn = wv slice
    f32x4 o = {0.f, 0.f, 0.f, 0.f};
    #pragma unroll
    for (int w = 0; w < 4; w++) {
        const f32x4 pOb = Ob4[(w * 4 + wv) * 64 + lane];
        #pragma unroll
        for (int r = 0; r < 4; r++) o[r] = fmaf(coef[w][r], pOb[r], o[r]);
    }
    #pragma unroll
    for (int r = 0; r < 4; r++) {
        const int i = i0 + 4 * quad + r;
        const size_t oo = (size_t)(b * Nn + i) * Dd + h * HDd + 16 * wv + lm;
        const u32_t p = pack32(o[r] * invL[r]);
        aoh[oo] = (u16_t)(p >> 16);
        aol[oo] = (u16_t)(p & 0xffffu);
    }
}

// ---------- K6: out = ao @ w_proj^T + bias, LDS-staged ----------
__global__ __launch_bounds__(256) void out_mfma(const u16_t* __restrict__ ah_, const u16_t* __restrict__ al_,
                                                const u16_t* __restrict__ wh, const u16_t* __restrict__ wl,
                                                const float* __restrict__ bias,
                                                float* __restrict__ out) {
    __shared__ __align__(16) u16_t Ah[64 * 72], Al[64 * 72], Bh[64 * 72], Bl[64 * 72];
    const int tid = threadIdx.x, lane = tid & 63, wv = tid >> 6;
    const int lm = lane & 15, quad = lane >> 4;
    const int mh = wv >> 1, nh = wv & 1;
    const int m0 = blockIdx.y * 64, c0 = blockIdx.x * 64;
    const int row = tid >> 2, co = (tid & 3) * 8;

    f32x4 acc[2][2];
    #pragma unroll
    for (int mt = 0; mt < 2; mt++)
        #pragma unroll
        for (int nt = 0; nt < 2; nt++) acc[mt][nt] = {0.f, 0.f, 0.f, 0.f};

    for (int kt = 0; kt < 8; kt++) {
        __syncthreads();
        const size_t ga = (size_t)(m0 + row) * Dd + kt * 64 + co;
        const size_t gb_ = (size_t)(c0 + row) * Dd + kt * 64 + co;
        *(uint4*)&Ah[row * 72 + co]      = *(const uint4*)(ah_ + ga);
        *(uint4*)&Ah[row * 72 + co + 32] = *(const uint4*)(ah_ + ga + 32);
        *(uint4*)&Al[row * 72 + co]      = *(const uint4*)(al_ + ga);
        *(uint4*)&Al[row * 72 + co + 32] = *(const uint4*)(al_ + ga + 32);
        *(uint4*)&Bh[row * 72 + co]      = *(const uint4*)(wh + gb_);
        *(uint4*)&Bh[row * 72 + co + 32] = *(const uint4*)(wh + gb_ + 32);
        *(uint4*)&Bl[row * 72 + co]      = *(const uint4*)(wl + gb_);
        *(uint4*)&Bl[row * 72 + co + 32] = *(const uint4*)(wl + gb_ + 32);
        __syncthreads();
        s16x8 ah[2][2], al[2][2];
        #pragma unroll
        for (int mt = 0; mt < 2; mt++)
            #pragma unroll
            for (int ks = 0; ks < 2; ks++) {
                const int o = (32 * mh + 16 * mt + lm) * 72 + ks * 32 + quad * 8;
                ah[mt][ks] = *(const s16x8*)&Ah[o];
                al[mt][ks] = *(const s16x8*)&Al[o];
            }
        #pragma unroll
        for (int nt = 0; nt < 2; nt++)
            #pragma unroll
            for (int ks = 0; ks < 2; ks++) {
                const int o = (32 * nh + 16 * nt + lm) * 72 + ks * 32 + quad * 8;
                s16x8 bh = *(const s16x8*)&Bh[o];
                s16x8 bl = *(const s16x8*)&Bl[o];
                #pragma unroll
                for (int mt = 0; mt < 2; mt++) {
                    acc[mt][nt] = MFMA(ah[mt][ks], bh, acc[mt][nt]);
                    acc[mt][nt] = MFMA(ah[mt][ks], bl, acc[mt][nt]);
                    acc[mt][nt] = MFMA(al[mt][ks], bh, acc[mt][nt]);
                }
            }
    }
    #pragma unroll
    for (int nt = 0; nt < 2; nt++) {
        const int c = c0 + 32 * nh + 16 * nt + lm;
        const float bc = bias[c];
        #pragma unroll
        for (int mt = 0; mt < 2; mt++)
            #pragma unroll
            for (int r = 0; r < 4; r++) {
                const int m = m0 + 32 * mh + 16 * mt + 4 * quad + r;
                out[(size_t)m * Dd + c] = acc[mt][nt][r] + bc;
            }
    }
}

extern "C" void kernel_launch(void* const* d_in, const int* in_sizes, int n_in,
                              void* d_out, int out_size, void* d_ws, size_t ws_size,
                              hipStream_t stream) {
    const float* x    = (const float*)d_in[0];
    const float* ef   = (const float*)d_in[1];
    const void*  msk  = d_in[2];
    const float* wqkv = (const float*)d_in[3];
    const float* wep  = (const float*)d_in[4];
    const float* weg  = (const float*)d_in[5];
    const float* beg  = (const float*)d_in[6];
    const float* wpj  = (const float*)d_in[7];
    const float* bpj  = (const float*)d_in[8];
    float* out = (float*)d_out;

    u8_t* p = (u8_t*)d_ws;
    int* mw    = (int*)p;           p += 16384;
    int* anyB  = (int*)p;           p += 256;
    u16_t* xh  = (u16_t*)p;         p += 4194304;
    u16_t* xl  = (u16_t*)p;         p += 4194304;
    u16_t* wqh = (u16_t*)p;         p += 1572864;
    u16_t* wql = (u16_t*)p;         p += 1572864;
    u16_t* wph = (u16_t*)p;         p += 524288;
    u16_t* wpl = (u16_t*)p;         p += 524288;
    u16_t* qhp = (u16_t*)p;         p += 4194304;
    u16_t* qlp = (u16_t*)p;         p += 4194304;
    u16_t* khp = (u16_t*)p;         p += 4194304;
    u16_t* klp = (u16_t*)p;         p += 4194304;
    u16_t* vhp = (u16_t*)p;         p += 4194304;
    u16_t* vlp = (u16_t*)p;         p += 4194304;
    u16_t* vth = (u16_t*)p;         p += 4194304;
    u16_t* vtl = (u16_t*)p;         p += 4194304;
    u16_t* gbp = (u16_t*)p;         p += 67108864;
    u16_t* aoh = (u16_t*)p;         p += 4194304;
    u16_t* aol = (u16_t*)p;         p += 4194304;

    prep_mask<<<1, 256, 0, stream>>>(msk, mw, anyB);
    presplit<<<12288, 256, 0, stream>>>(x, wqkv, wpj, xh, xl, wqh, wql, wph, wpl);
    gb_pre<<<4096, 256, 0, stream>>>(ef, wep, weg, beg, gbp);
    qkv_mfma<<<dim3(24, 64), 256, 0, stream>>>(xh, xl, wqh, wql,
                                               qhp, qlp, khp, klp, vhp, vlp);
    vt_trans<<<dim3(16, Bb * Hh), 256, 0, stream>>>(vhp, vlp, vth, vtl);
    attn_mfma<<<dim3(Nn / 16, Hh, Bb), 256, 0, stream>>>(qhp, qlp, khp, klp, vth, vtl,
                                                         gbp, mw, anyB, aoh, aol);
    out_mfma<<<dim3(8, 64), 256, 0, stream>>>(aoh, aol, wph, wpl, bpj, out);
}